// Round 2
// baseline (1981.766 us; speedup 1.0000x reference)
//
#include <hip/hip_runtime.h>
#include <cstdint>

#define NTHREADS 256
#define TBL_SIZE (1u << 19)
#define HIDDEN 64

struct Levels { float scale[16]; int res[16]; int dense[16]; };
constexpr Levels make_levels() {
    Levels L{};
    double s = 16.0;
    for (int l = 0; l < 16; ++l) {
        double sc = s - 1.0;
        L.scale[l] = (float)sc;
        int fi = (int)sc;
        int res = fi + (((double)fi < sc) ? 1 : 0) + 1;   // ceil(sc)+1
        L.res[l] = res;
        L.dense[l] = ((long long)res * res * res <= (long long)TBL_SIZE) ? 1 : 0;
        s *= 1.3819;
    }
    return L;
}
constexpr Levels LV = make_levels();

__global__ __launch_bounds__(NTHREADS, 3) void sdf_tcnn_fused(
    const float* __restrict__ x,
    const float* __restrict__ table,
    const float* __restrict__ W1, const float* __restrict__ b1,
    const float* __restrict__ W2, const float* __restrict__ b2,
    const float* __restrict__ W3, const float* __restrict__ b3,
    float* __restrict__ out, int n)
{
    const int i = blockIdx.x * NTHREADS + threadIdx.x;
    if (i >= n) return;

    const float xi = x[3 * i + 0];
    const float yi = x[3 * i + 1];
    const float zi = x[3 * i + 2];
    const float u = (xi + 1.0f) * 0.5f;
    const float v = (yi + 1.0f) * 0.5f;
    const float w = (zi + 1.0f) * 0.5f;

    // h1 accumulates layer-1 pre-activation; layer-1 fused into the level loop.
    // All weight/bias reads below are wave-uniform -> scalar loads via K$.
    float h1[HIDDEN];
    #pragma unroll
    for (int j = 0; j < HIDDEN; j += 4) {
        const float4 bb = *(const float4*)&b1[j];
        h1[j + 0] = bb.x; h1[j + 1] = bb.y; h1[j + 2] = bb.z; h1[j + 3] = bb.w;
    }

    #pragma unroll
    for (int l = 0; l < 16; ++l) {
        const float sc = LV.scale[l];
        const int res = LV.res[l];
        const float pu = u * sc + 0.5f;
        const float pv = v * sc + 0.5f;
        const float pw = w * sc + 0.5f;
        const float fu = floorf(pu), fv = floorf(pv), fw = floorf(pw);
        const float wu = pu - fu, wv = pv - fv, ww = pw - fw;
        const int iu = (int)fu, iv = (int)fv, iw = (int)fw;

        const float2* tl = (const float2*)(table + (size_t)l * TBL_SIZE * 2);

        // compute 8 corner indices, then issue all 8 loads back-to-back (ILP)
        int idx[8];
        #pragma unroll
        for (int b = 0; b < 8; ++b) {
            const int o0 = (b >> 2) & 1, o1 = (b >> 1) & 1, o2 = b & 1;
            if (LV.dense[l]) {
                idx[b] = (iu + o0) + (iv + o1) * res + (iw + o2) * (res * res);
            } else {
                const uint32_t c0 = (uint32_t)(iu + o0);
                const uint32_t c1 = (uint32_t)(iv + o1);
                const uint32_t c2 = (uint32_t)(iw + o2);
                const uint32_t h = c0 ^ (c1 * 2654435761u) ^ (c2 * 805459861u);
                idx[b] = (int)(h & (TBL_SIZE - 1u));
            }
        }
        float2 cf[8];
        #pragma unroll
        for (int b = 0; b < 8; ++b) cf[b] = tl[idx[b]];

        float f0 = 0.0f, f1 = 0.0f;
        #pragma unroll
        for (int b = 0; b < 8; ++b) {
            const int o0 = (b >> 2) & 1, o1 = (b >> 1) & 1, o2 = b & 1;
            const float wt = (o0 ? wu : 1.0f - wu) *
                             (o1 ? wv : 1.0f - wv) *
                             (o2 ? ww : 1.0f - ww);
            f0 = fmaf(cf[b].x, wt, f0);
            f1 = fmaf(cf[b].y, wt, f1);
        }

        // fused layer-1 rank-1 updates: h1 += f0 * W1[2l,:] + f1 * W1[2l+1,:]
        // W1 rows read uniformly from global (scalar-cache path).
        const float* wra = &W1[(2 * l) * HIDDEN];
        const float* wrb = &W1[(2 * l + 1) * HIDDEN];
        #pragma unroll
        for (int j = 0; j < HIDDEN; j += 4) {
            const float4 wa = *(const float4*)&wra[j];
            const float4 wb = *(const float4*)&wrb[j];
            h1[j + 0] = fmaf(f0, wa.x, fmaf(f1, wb.x, h1[j + 0]));
            h1[j + 1] = fmaf(f0, wa.y, fmaf(f1, wb.y, h1[j + 1]));
            h1[j + 2] = fmaf(f0, wa.z, fmaf(f1, wb.z, h1[j + 2]));
            h1[j + 3] = fmaf(f0, wa.w, fmaf(f1, wb.w, h1[j + 3]));
        }
    }

    // ReLU layer 1
    #pragma unroll
    for (int j = 0; j < HIDDEN; ++j) h1[j] = fmaxf(h1[j], 0.0f);

    // layers 2+3 fused, j-blocked by 4 so live state stays h1[64] + 4 accs.
    float acc = b3[0];
    #pragma unroll
    for (int j = 0; j < HIDDEN; j += 4) {
        const float4 bb = *(const float4*)&b2[j];
        float t0 = bb.x, t1 = bb.y, t2 = bb.z, t3 = bb.w;
        #pragma unroll 8
        for (int k = 0; k < HIDDEN; ++k) {
            const float4 wr = *(const float4*)&W2[k * HIDDEN + j];
            const float hk = h1[k];
            t0 = fmaf(hk, wr.x, t0);
            t1 = fmaf(hk, wr.y, t1);
            t2 = fmaf(hk, wr.z, t2);
            t3 = fmaf(hk, wr.w, t3);
        }
        const float4 w3 = *(const float4*)&W3[j];
        acc = fmaf(fmaxf(t0, 0.0f), w3.x, acc);
        acc = fmaf(fmaxf(t1, 0.0f), w3.y, acc);
        acc = fmaf(fmaxf(t2, 0.0f), w3.z, acc);
        acc = fmaf(fmaxf(t3, 0.0f), w3.w, acc);
    }

    out[i] = acc;
}

extern "C" void kernel_launch(void* const* d_in, const int* in_sizes, int n_in,
                              void* d_out, int out_size, void* d_ws, size_t ws_size,
                              hipStream_t stream) {
    const float* x     = (const float*)d_in[0];
    const float* table = (const float*)d_in[1];
    const float* W1    = (const float*)d_in[2];
    const float* b1    = (const float*)d_in[3];
    const float* W2    = (const float*)d_in[4];
    const float* b2    = (const float*)d_in[5];
    const float* W3    = (const float*)d_in[6];
    const float* b3    = (const float*)d_in[7];
    float* out = (float*)d_out;

    const int n = in_sizes[0] / 3;
    dim3 grid((n + NTHREADS - 1) / NTHREADS);
    hipLaunchKernelGGL(sdf_tcnn_fused, grid, dim3(NTHREADS), 0, stream,
                       x, table, W1, b1, W2, b2, W3, b3, out, n);
}

// Round 3
// 848.848 us; speedup vs baseline: 2.3347x; 2.3347x over previous
//
#include <hip/hip_runtime.h>
#include <cstdint>

#define NTHREADS 256
#define TBL_SIZE (1u << 19)
#define HIDDEN 64

struct Levels { float scale[16]; int res[16]; int dense[16]; };
constexpr Levels make_levels() {
    Levels L{};
    double s = 16.0;
    for (int l = 0; l < 16; ++l) {
        double sc = s - 1.0;
        L.scale[l] = (float)sc;
        int fi = (int)sc;
        int res = fi + (((double)fi < sc) ? 1 : 0) + 1;   // ceil(sc)+1
        L.res[l] = res;
        L.dense[l] = ((long long)res * res * res <= (long long)TBL_SIZE) ? 1 : 0;
        s *= 1.3819;
    }
    return L;
}
constexpr Levels LV = make_levels();

// expand M(m) for m = 0..15 — h1 lives in 16 NAMED float4s (never an array,
// so nothing can be demoted to scratch; rule: no runtime-indexed locals)
#define H16(M) M(0) M(1) M(2) M(3) M(4) M(5) M(6) M(7) \
               M(8) M(9) M(10) M(11) M(12) M(13) M(14) M(15)

__global__ __launch_bounds__(NTHREADS, 3) void sdf_tcnn_fused(
    const float* __restrict__ x,
    const float* __restrict__ table,
    const float* __restrict__ W1, const float* __restrict__ b1,
    const float* __restrict__ W2, const float* __restrict__ b2,
    const float* __restrict__ W3, const float* __restrict__ b3,
    float* __restrict__ out, int n)
{
    const int i = blockIdx.x * NTHREADS + threadIdx.x;
    if (i >= n) return;

    const float u = (x[3 * i + 0] + 1.0f) * 0.5f;
    const float v = (x[3 * i + 1] + 1.0f) * 0.5f;
    const float w = (x[3 * i + 2] + 1.0f) * 0.5f;

    // ---- h1 pre-activation accumulators: 16 named float4s ----
#define DECLH(m) float4 h##m = *(const float4*)&b1[4 * (m)];
    H16(DECLH)
#undef DECLH

    #pragma unroll
    for (int l = 0; l < 16; ++l) {
        const float sc = LV.scale[l];
        const int res = LV.res[l];
        const float pu = u * sc + 0.5f;
        const float pv = v * sc + 0.5f;
        const float pw = w * sc + 0.5f;
        const float fu = floorf(pu), fv = floorf(pv), fw = floorf(pw);
        const float wu = pu - fu, wv = pv - fv, ww = pw - fw;
        const int iu = (int)fu, iv = (int)fv, iw = (int)fw;

        const float2* tl = (const float2*)(table + (size_t)l * TBL_SIZE * 2);

        int idx[8];
        #pragma unroll
        for (int b = 0; b < 8; ++b) {
            const int o0 = (b >> 2) & 1, o1 = (b >> 1) & 1, o2 = b & 1;
            if (LV.dense[l]) {
                idx[b] = (iu + o0) + (iv + o1) * res + (iw + o2) * (res * res);
            } else {
                const uint32_t c0 = (uint32_t)(iu + o0);
                const uint32_t c1 = (uint32_t)(iv + o1);
                const uint32_t c2 = (uint32_t)(iw + o2);
                const uint32_t h = c0 ^ (c1 * 2654435761u) ^ (c2 * 805459861u);
                idx[b] = (int)(h & (TBL_SIZE - 1u));
            }
        }
        float2 cf[8];
        #pragma unroll
        for (int b = 0; b < 8; ++b) cf[b] = tl[idx[b]];

        float f0 = 0.0f, f1 = 0.0f;
        #pragma unroll
        for (int b = 0; b < 8; ++b) {
            const int o0 = (b >> 2) & 1, o1 = (b >> 1) & 1, o2 = b & 1;
            const float wt = (o0 ? wu : 1.0f - wu) *
                             (o1 ? wv : 1.0f - wv) *
                             (o2 ? ww : 1.0f - ww);
            f0 = fmaf(cf[b].x, wt, f0);
            f1 = fmaf(cf[b].y, wt, f1);
        }

        // fused layer-1 rank-1 update: h += f0*W1[2l,:] + f1*W1[2l+1,:]
        const float* wra = &W1[(2 * l) * HIDDEN];
        const float* wrb = &W1[(2 * l + 1) * HIDDEN];
#define UPDH(m) { \
        const float4 wa = *(const float4*)&wra[4 * (m)]; \
        const float4 wb = *(const float4*)&wrb[4 * (m)]; \
        h##m.x = fmaf(f0, wa.x, fmaf(f1, wb.x, h##m.x)); \
        h##m.y = fmaf(f0, wa.y, fmaf(f1, wb.y, h##m.y)); \
        h##m.z = fmaf(f0, wa.z, fmaf(f1, wb.z, h##m.z)); \
        h##m.w = fmaf(f0, wa.w, fmaf(f1, wb.w, h##m.w)); }
        H16(UPDH)
#undef UPDH
    }

    // ReLU
#define RELUH(m) { h##m.x = fmaxf(h##m.x, 0.0f); h##m.y = fmaxf(h##m.y, 0.0f); \
                   h##m.z = fmaxf(h##m.z, 0.0f); h##m.w = fmaxf(h##m.w, 0.0f); }
    H16(RELUH)
#undef RELUH

    // layers 2+3: jb loop kept ROLLED (code size); k fully static via macro.
    // W2/W3/b2 addresses are lane-uniform -> scalar K$ loads.
    float acc = b3[0];
    #pragma unroll 2
    for (int jb = 0; jb < HIDDEN; jb += 4) {
        float4 t = *(const float4*)&b2[jb];
#define L2K(m) { \
        const float4 r0 = *(const float4*)&W2[(4 * (m) + 0) * HIDDEN + jb]; \
        const float4 r1 = *(const float4*)&W2[(4 * (m) + 1) * HIDDEN + jb]; \
        const float4 r2 = *(const float4*)&W2[(4 * (m) + 2) * HIDDEN + jb]; \
        const float4 r3 = *(const float4*)&W2[(4 * (m) + 3) * HIDDEN + jb]; \
        t.x = fmaf(h##m.x, r0.x, t.x); t.y = fmaf(h##m.x, r0.y, t.y); \
        t.z = fmaf(h##m.x, r0.z, t.z); t.w = fmaf(h##m.x, r0.w, t.w); \
        t.x = fmaf(h##m.y, r1.x, t.x); t.y = fmaf(h##m.y, r1.y, t.y); \
        t.z = fmaf(h##m.y, r1.z, t.z); t.w = fmaf(h##m.y, r1.w, t.w); \
        t.x = fmaf(h##m.z, r2.x, t.x); t.y = fmaf(h##m.z, r2.y, t.y); \
        t.z = fmaf(h##m.z, r2.z, t.z); t.w = fmaf(h##m.z, r2.w, t.w); \
        t.x = fmaf(h##m.w, r3.x, t.x); t.y = fmaf(h##m.w, r3.y, t.y); \
        t.z = fmaf(h##m.w, r3.z, t.z); t.w = fmaf(h##m.w, r3.w, t.w); }
        H16(L2K)
#undef L2K
        const float4 w3v = *(const float4*)&W3[jb];
        acc = fmaf(fmaxf(t.x, 0.0f), w3v.x, acc);
        acc = fmaf(fmaxf(t.y, 0.0f), w3v.y, acc);
        acc = fmaf(fmaxf(t.z, 0.0f), w3v.z, acc);
        acc = fmaf(fmaxf(t.w, 0.0f), w3v.w, acc);
    }

    out[i] = acc;
}

extern "C" void kernel_launch(void* const* d_in, const int* in_sizes, int n_in,
                              void* d_out, int out_size, void* d_ws, size_t ws_size,
                              hipStream_t stream) {
    const float* x     = (const float*)d_in[0];
    const float* table = (const float*)d_in[1];
    const float* W1    = (const float*)d_in[2];
    const float* b1    = (const float*)d_in[3];
    const float* W2    = (const float*)d_in[4];
    const float* b2    = (const float*)d_in[5];
    const float* W3    = (const float*)d_in[6];
    const float* b3    = (const float*)d_in[7];
    float* out = (float*)d_out;

    const int n = in_sizes[0] / 3;
    dim3 grid((n + NTHREADS - 1) / NTHREADS);
    hipLaunchKernelGGL(sdf_tcnn_fused, grid, dim3(NTHREADS), 0, stream,
                       x, table, W1, b1, W2, b2, W3, b3, out, n);
}

// Round 4
// 665.838 us; speedup vs baseline: 2.9763x; 1.2749x over previous
//
#include <hip/hip_runtime.h>
#include <hip/hip_fp16.h>
#include <cstdint>

#define NTHREADS 256
#define TBL_SIZE (1u << 19)
#define HIDDEN 64

struct Levels { float scale[16]; int res[16]; int dense[16]; };
constexpr Levels make_levels() {
    Levels L{};
    double s = 16.0;
    for (int l = 0; l < 16; ++l) {
        double sc = s - 1.0;
        L.scale[l] = (float)sc;
        int fi = (int)sc;
        int res = fi + (((double)fi < sc) ? 1 : 0) + 1;   // ceil(sc)+1
        L.res[l] = res;
        L.dense[l] = ((long long)res * res * res <= (long long)TBL_SIZE) ? 1 : 0;
        s *= 1.3819;
    }
    return L;
}
constexpr Levels LV = make_levels();

// expand M(m) for m = 0..15 — h1 lives in 16 NAMED float4s (no runtime-indexed locals)
#define H16(M) M(0) M(1) M(2) M(3) M(4) M(5) M(6) M(7) \
               M(8) M(9) M(10) M(11) M(12) M(13) M(14) M(15)

// f32 table -> fp16 repack (runs every launch; stream-ordered before main kernel)
__global__ __launch_bounds__(256) void cvt_table(const float2* __restrict__ in,
                                                 __half2* __restrict__ out, int n) {
    for (int i = blockIdx.x * 256 + threadIdx.x; i < n; i += gridDim.x * 256) {
        const float2 v = in[i];
        out[i] = __floats2half2_rn(v.x, v.y);
    }
}

template <bool USE_H2>
__global__ __launch_bounds__(NTHREADS, 4) void sdf_tcnn_fused(
    const float* __restrict__ x,
    const void* __restrict__ tbl,
    const float* __restrict__ W1, const float* __restrict__ b1,
    const float* __restrict__ W2, const float* __restrict__ b2,
    const float* __restrict__ W3, const float* __restrict__ b3,
    float* __restrict__ out, int n)
{
    const int i = blockIdx.x * NTHREADS + threadIdx.x;
    if (i >= n) return;

    const float u = (x[3 * i + 0] + 1.0f) * 0.5f;
    const float v = (x[3 * i + 1] + 1.0f) * 0.5f;
    const float w = (x[3 * i + 2] + 1.0f) * 0.5f;

#define DECLH(m) float4 h##m = *(const float4*)&b1[4 * (m)];
    H16(DECLH)
#undef DECLH

    #pragma unroll
    for (int l = 0; l < 16; ++l) {
        const float sc = LV.scale[l];
        const int res = LV.res[l];
        const float pu = u * sc + 0.5f;
        const float pv = v * sc + 0.5f;
        const float pw = w * sc + 0.5f;
        const float fu = floorf(pu), fv = floorf(pv), fw = floorf(pw);
        const float wu = pu - fu, wv = pv - fv, ww = pw - fw;
        const int iu = (int)fu, iv = (int)fv, iw = (int)fw;

        int idx[8];
        #pragma unroll
        for (int b = 0; b < 8; ++b) {
            const int o0 = (b >> 2) & 1, o1 = (b >> 1) & 1, o2 = b & 1;
            if (LV.dense[l]) {
                idx[b] = (iu + o0) + (iv + o1) * res + (iw + o2) * (res * res);
            } else {
                const uint32_t c0 = (uint32_t)(iu + o0);
                const uint32_t c1 = (uint32_t)(iv + o1);
                const uint32_t c2 = (uint32_t)(iw + o2);
                const uint32_t h = c0 ^ (c1 * 2654435761u) ^ (c2 * 805459861u);
                idx[b] = (int)(h & (TBL_SIZE - 1u));
            }
        }

        float f0 = 0.0f, f1 = 0.0f;
        if constexpr (USE_H2) {
            const __half2* tl = (const __half2*)tbl + (size_t)l * TBL_SIZE;
            __half2 cfh[8];
            #pragma unroll
            for (int b = 0; b < 8; ++b) cfh[b] = tl[idx[b]];   // 8 x 4B gathers, back-to-back
            #pragma unroll
            for (int b = 0; b < 8; ++b) {
                const int o0 = (b >> 2) & 1, o1 = (b >> 1) & 1, o2 = b & 1;
                const float wt = (o0 ? wu : 1.0f - wu) *
                                 (o1 ? wv : 1.0f - wv) *
                                 (o2 ? ww : 1.0f - ww);
                const float2 cf = __half22float2(cfh[b]);
                f0 = fmaf(cf.x, wt, f0);
                f1 = fmaf(cf.y, wt, f1);
            }
        } else {
            const float2* tl = (const float2*)tbl + (size_t)l * TBL_SIZE;
            float2 cf[8];
            #pragma unroll
            for (int b = 0; b < 8; ++b) cf[b] = tl[idx[b]];
            #pragma unroll
            for (int b = 0; b < 8; ++b) {
                const int o0 = (b >> 2) & 1, o1 = (b >> 1) & 1, o2 = b & 1;
                const float wt = (o0 ? wu : 1.0f - wu) *
                                 (o1 ? wv : 1.0f - wv) *
                                 (o2 ? ww : 1.0f - ww);
                f0 = fmaf(cf[b].x, wt, f0);
                f1 = fmaf(cf[b].y, wt, f1);
            }
        }

        // fused layer-1 rank-1 update (weights via scalar K$ loads)
        const float* wra = &W1[(2 * l) * HIDDEN];
        const float* wrb = &W1[(2 * l + 1) * HIDDEN];
#define UPDH(m) { \
        const float4 wa = *(const float4*)&wra[4 * (m)]; \
        const float4 wb = *(const float4*)&wrb[4 * (m)]; \
        h##m.x = fmaf(f0, wa.x, fmaf(f1, wb.x, h##m.x)); \
        h##m.y = fmaf(f0, wa.y, fmaf(f1, wb.y, h##m.y)); \
        h##m.z = fmaf(f0, wa.z, fmaf(f1, wb.z, h##m.z)); \
        h##m.w = fmaf(f0, wa.w, fmaf(f1, wb.w, h##m.w)); }
        H16(UPDH)
#undef UPDH
    }

#define RELUH(m) { h##m.x = fmaxf(h##m.x, 0.0f); h##m.y = fmaxf(h##m.y, 0.0f); \
                   h##m.z = fmaxf(h##m.z, 0.0f); h##m.w = fmaxf(h##m.w, 0.0f); }
    H16(RELUH)
#undef RELUH

    // layers 2+3: jb rolled (code size); k static via macro; weights via K$.
    float acc = b3[0];
    #pragma unroll 2
    for (int jb = 0; jb < HIDDEN; jb += 4) {
        float4 t = *(const float4*)&b2[jb];
#define L2K(m) { \
        const float4 r0 = *(const float4*)&W2[(4 * (m) + 0) * HIDDEN + jb]; \
        const float4 r1 = *(const float4*)&W2[(4 * (m) + 1) * HIDDEN + jb]; \
        const float4 r2 = *(const float4*)&W2[(4 * (m) + 2) * HIDDEN + jb]; \
        const float4 r3 = *(const float4*)&W2[(4 * (m) + 3) * HIDDEN + jb]; \
        t.x = fmaf(h##m.x, r0.x, t.x); t.y = fmaf(h##m.x, r0.y, t.y); \
        t.z = fmaf(h##m.x, r0.z, t.z); t.w = fmaf(h##m.x, r0.w, t.w); \
        t.x = fmaf(h##m.y, r1.x, t.x); t.y = fmaf(h##m.y, r1.y, t.y); \
        t.z = fmaf(h##m.y, r1.z, t.z); t.w = fmaf(h##m.y, r1.w, t.w); \
        t.x = fmaf(h##m.z, r2.x, t.x); t.y = fmaf(h##m.z, r2.y, t.y); \
        t.z = fmaf(h##m.z, r2.z, t.z); t.w = fmaf(h##m.z, r2.w, t.w); \
        t.x = fmaf(h##m.w, r3.x, t.x); t.y = fmaf(h##m.w, r3.y, t.y); \
        t.z = fmaf(h##m.w, r3.z, t.z); t.w = fmaf(h##m.w, r3.w, t.w); }
        H16(L2K)
#undef L2K
        const float4 w3v = *(const float4*)&W3[jb];
        acc = fmaf(fmaxf(t.x, 0.0f), w3v.x, acc);
        acc = fmaf(fmaxf(t.y, 0.0f), w3v.y, acc);
        acc = fmaf(fmaxf(t.z, 0.0f), w3v.z, acc);
        acc = fmaf(fmaxf(t.w, 0.0f), w3v.w, acc);
    }

    out[i] = acc;
}

extern "C" void kernel_launch(void* const* d_in, const int* in_sizes, int n_in,
                              void* d_out, int out_size, void* d_ws, size_t ws_size,
                              hipStream_t stream) {
    const float* x     = (const float*)d_in[0];
    const float* table = (const float*)d_in[1];
    const float* W1    = (const float*)d_in[2];
    const float* b1    = (const float*)d_in[3];
    const float* W2    = (const float*)d_in[4];
    const float* b2    = (const float*)d_in[5];
    const float* W3    = (const float*)d_in[6];
    const float* b3    = (const float*)d_in[7];
    float* out = (float*)d_out;

    const int n = in_sizes[0] / 3;
    const int n_entries = 16 * (int)TBL_SIZE;              // 8.4M float2 entries
    const size_t need = (size_t)n_entries * sizeof(__half2);
    dim3 grid((n + NTHREADS - 1) / NTHREADS);

    if (ws_size >= need) {
        __half2* tbl_h2 = (__half2*)d_ws;
        hipLaunchKernelGGL(cvt_table, dim3(2048), dim3(256), 0, stream,
                           (const float2*)table, tbl_h2, n_entries);
        hipLaunchKernelGGL((sdf_tcnn_fused<true>), grid, dim3(NTHREADS), 0, stream,
                           x, (const void*)tbl_h2, W1, b1, W2, b2, W3, b3, out, n);
    } else {
        hipLaunchKernelGGL((sdf_tcnn_fused<false>), grid, dim3(NTHREADS), 0, stream,
                           x, (const void*)table, W1, b1, W2, b2, W3, b3, out, n);
    }
}